// Round 8
// baseline (340.085 us; speedup 1.0000x reference)
//
#include <hip/hip_runtime.h>

// out[b,m,f,t] = sum_c W[m,f,c] * x[b,m,c,t]
// x: [B=256][NM=5][NC=64][T=1024] f32, W: [NM=5][NF=40][NC=64] f32
// out: [B][NM][NF=40][T] f32
//
// R7: defeat the AGPR-demotion policy structurally. R2/R4/R6 all show the
// backend holding arch-VGPRs at 32-44 and shuffling the 40-float acc array
// through AGPRs (v_accvgpr_read/write per FMA -> 3x VALU, 97+ us VALU busy).
// Fix: wave-level f-tiling. Each wave owns 10 f's -> per-thread state is
// 10 float2 accs (~45 VGPR total demand), which fits any budget honestly.
// Block = 4 waves x (bm, 128-t tile); all waves read the same 32 KB x tile
// (L1-resident). 8 blocks/CU (waves_per_eu(8)) -> 2048 resident blocks,
// grid 10240 = exactly 5 generations, no dispatch tail, 32 waves/CU.

#define B_  256
#define NM_ 5
#define NC_ 64
#define T_  1024
#define NF_ 40
#define FW_ 10        // f's per wave
#define TT_ 128       // t's per block tile
#define CCHUNK 4

typedef float v2f __attribute__((ext_vector_type(2)));

__global__ __launch_bounds__(256)
__attribute__((amdgpu_waves_per_eu(8)))
void trca_einsum_kernel(
    const float* __restrict__ x,
    const float* __restrict__ W,
    float* __restrict__ out)
{
    const int lane  = threadIdx.x & 63;
    const int wv    = threadIdx.x >> 6;      // 0..3
    const int ttile = blockIdx.x & 7;        // 8 tiles of 128 t
    const int bm    = blockIdx.x >> 3;       // b*NM + m
    const int m     = bm % NM_;
    const int t0    = ttile * TT_ + lane * 2;

    const float* __restrict__ xp = x + (size_t)bm * NC_ * T_ + t0;          // stride T_ per c
    const float* __restrict__ wp = W + (size_t)m * NF_ * NC_ + wv * FW_ * NC_;
    float* __restrict__ op = out + (size_t)bm * NF_ * T_ + (size_t)wv * FW_ * T_ + t0;

    float acc0[FW_], acc1[FW_];
#pragma unroll
    for (int f = 0; f < FW_; ++f) { acc0[f] = 0.0f; acc1[f] = 0.0f; }

#pragma unroll 1
    for (int cc = 0; cc < NC_; cc += CCHUNK) {
        v2f xv[CCHUNK];
#pragma unroll
        for (int i = 0; i < CCHUNK; ++i)
            xv[i] = *reinterpret_cast<const v2f*>(xp + (size_t)(cc + i) * T_);
#pragma unroll
        for (int i = 0; i < CCHUNK; ++i) {
#pragma unroll
            for (int f = 0; f < FW_; ++f) {
                const float w = wp[f * NC_ + cc + i];   // wave-uniform -> s_load
                acc0[f] += w * xv[i][0];
                acc1[f] += w * xv[i][1];
            }
        }
    }

#pragma unroll
    for (int f = 0; f < FW_; ++f) {
        v2f v; v[0] = acc0[f]; v[1] = acc1[f];
        __builtin_nontemporal_store(v, reinterpret_cast<v2f*>(op + (size_t)f * T_));
    }
}

extern "C" void kernel_launch(void* const* d_in, const int* in_sizes, int n_in,
                              void* d_out, int out_size, void* d_ws, size_t ws_size,
                              hipStream_t stream)
{
    const float* x = (const float*)d_in[0];
    const float* W = (const float*)d_in[1];
    float* out = (float*)d_out;

    const int grid = B_ * NM_ * (T_ / TT_);   // 10240 blocks
    trca_einsum_kernel<<<grid, 256, 0, stream>>>(x, W, out);
}